// Round 13
// baseline (771.642 us; speedup 1.0000x reference)
//
#include <hip/hip_runtime.h>
#include <hip/hip_bf16.h>

typedef __attribute__((ext_vector_type(8))) _Float16 half8;
typedef __attribute__((ext_vector_type(4))) float f32x4;

#define N_NODES 100000
#define N_EDGES 1600000
#define IN_CH 1024
#define FEAT 128
#define CAP 64
#define NDIG 196               // coarse digits: dst>>9
#define CAPC 10240             // coarse segment capacity
#define NTILES ((N_NODES + 127) / 128)   // 782

// W1t[col][k] = fp16 W1[k][col]; init coarse cursors + done flag
__global__ void k_prep(const float* __restrict__ W1, _Float16* __restrict__ W1t,
                       int* __restrict__ cursorC, int* __restrict__ done) {
    int idx = blockIdx.x * 256 + threadIdx.x;
    if (idx < IN_CH * FEAT) {
        int col = idx & (FEAT - 1), k = idx >> 7;
        W1t[(size_t)col * IN_CH + k] = (_Float16)W1[idx];
    }
    if (idx < NDIG) cursorC[idx] = idx * CAPC;
    if (idx == 0) *done = 0;
}

// Role-split kernel. GEMM K-loop uses lgkm-only barrier (no vmcnt drain) +
// 2-deep A prefetch: A loads stay in flight ACROSS barriers (T4-lite).
__global__ __launch_bounds__(256, 2) void k_build_gemm(
    const float* __restrict__ A, const _Float16* __restrict__ Bt,
    const int4* __restrict__ src4, const int4* __restrict__ dst4,
    int* __restrict__ cursorC, uint2* __restrict__ recs,
    int* __restrict__ csr, int* __restrict__ cnt, float* __restrict__ dinvarr,
    int* __restrict__ done, _Float16* __restrict__ H, int M, int e4, int do_bin)
{
    __shared__ union {
        _Float16 Bs[2][128][72];
        struct { int hist[NDIG], segoff[NDIG], lcur[NDIG]; } bin;
        int cl[512];
    } sm;
    const int t = threadIdx.x;

    if (blockIdx.x < NDIG) {
        if (!do_bin) return;        // attribution re-launch: skip bin/csr
        // ================= bin phase =================
        const int b = blockIdx.x;
        if (t < NDIG) sm.bin.hist[t] = 0;
        __syncthreads();
        const int base4 = b * 2048;
        int4 sv[8], dv[8];
#pragma unroll
        for (int j = 0; j < 8; ++j) {
            int idx = base4 + j * 256 + t;
            if (idx < e4) { sv[j] = src4[idx]; dv[j] = dst4[idx]; }
            else { sv[j] = (int4){-1,-1,-1,-1}; dv[j] = (int4){-1,-1,-1,-1}; }
        }
#pragma unroll
        for (int j = 0; j < 8; ++j) {
            int dd[4] = {dv[j].x, dv[j].y, dv[j].z, dv[j].w};
            int ss[4] = {sv[j].x, sv[j].y, sv[j].z, sv[j].w};
#pragma unroll
            for (int c = 0; c < 4; ++c)
                if ((unsigned)dd[c] < N_NODES && (unsigned)ss[c] < N_NODES)
                    atomicAdd(&sm.bin.hist[dd[c] >> 9], 1);
        }
        __syncthreads();
        if (t < NDIG) {
            sm.bin.segoff[t] = atomicAdd(&cursorC[t], sm.bin.hist[t]);
            sm.bin.lcur[t] = 0;
        }
        __syncthreads();
#pragma unroll
        for (int j = 0; j < 8; ++j) {
            int dd[4] = {dv[j].x, dv[j].y, dv[j].z, dv[j].w};
            int ss[4] = {sv[j].x, sv[j].y, sv[j].z, sv[j].w};
#pragma unroll
            for (int c = 0; c < 4; ++c) {
                if ((unsigned)dd[c] < N_NODES && (unsigned)ss[c] < N_NODES) {
                    int dg = dd[c] >> 9;
                    int r = atomicAdd(&sm.bin.lcur[dg], 1);
                    int pos = sm.bin.segoff[dg] + r;
                    if (pos < (dg + 1) * CAPC)
                        recs[pos] = (uint2){(unsigned)ss[c], (unsigned)dd[c]};
                }
            }
        }
        __syncthreads();
        if (t == 0) {   // resident spin-barrier over the 196 bin blocks
            __threadfence();
            __hip_atomic_fetch_add(done, 1, __ATOMIC_RELEASE, __HIP_MEMORY_SCOPE_AGENT);
            while (__hip_atomic_load(done, __ATOMIC_ACQUIRE, __HIP_MEMORY_SCOPE_AGENT) < NDIG)
                __builtin_amdgcn_s_sleep(8);
        }
        __syncthreads();
        // ================= csr phase =================
        const int d = blockIdx.x;
        for (int j = t; j < 512; j += 256) sm.cl[j] = 0;
        __syncthreads();
        const int base = d * CAPC;
        int n = cursorC[d] - base;
        if (n > CAPC) n = CAPC;
        for (int k = t; k < n; k += 256) {
            uint2 r = recs[base + k];
            int local = (int)r.y & 511;
            int slot = atomicAdd(&sm.cl[local], 1);
            if (slot < CAP) csr[((int)r.y << 6) + slot] = (int)r.x;
        }
        __syncthreads();
        const int node0 = d << 9;
        for (int j = t; j < 512; j += 256) {
            int node = node0 + j;
            if (node < N_NODES) {
                int c = sm.cl[j] < CAP ? sm.cl[j] : CAP;
                cnt[node] = c;
                dinvarr[node] = rsqrtf((float)(c + 1));
            }
        }
        return;
    }

    // ================= GEMM role (pipelined) =================
    const int wid = t >> 6, lane = t & 63;
    const int brow0 = (blockIdx.x - NDIG) * 128;

    f32x4 acc[2][8];
#pragma unroll
    for (int m = 0; m < 2; ++m)
#pragma unroll
        for (int nn = 0; nn < 8; ++nn) acc[m][nn] = (f32x4){0.f, 0.f, 0.f, 0.f};

    int r0 = brow0 + wid * 32 + (lane & 15);
    int r1 = r0 + 16;
    if (r0 >= M) r0 = M - 1;
    if (r1 >= M) r1 = M - 1;
    const int kbase = (lane >> 4) * 8;
    const float* pa0 = A + (size_t)r0 * IN_CH + kbase;
    const float* pa1 = A + (size_t)r1 * IN_CH + kbase;
    const int bcol = t >> 1;
    const int bko = (t & 1) * 32;
    const _Float16* pb = Bt + (size_t)bcol * IN_CH + bko;

    float4 ar[2][2][2][2];   // [buf][m][kk][j] : 2-deep A prefetch
    half8 af[2][2];          // current converted A fragments
    half8 bst[4];            // B staging regs

#define LOAD_A(bi, kt)                                                          \
    {                                                                           \
        _Pragma("unroll") for (int m = 0; m < 2; ++m) {                         \
            const float* p_ = (m ? pa1 : pa0) + (kt) * 64;                      \
            _Pragma("unroll") for (int kk = 0; kk < 2; ++kk) {                  \
                ar[bi][m][kk][0] = *(const float4*)(p_ + kk * 32);              \
                ar[bi][m][kk][1] = *(const float4*)(p_ + kk * 32 + 4);          \
            }                                                                   \
        }                                                                       \
    }
#define CVT_A(bi)                                                               \
    {                                                                           \
        _Pragma("unroll") for (int m = 0; m < 2; ++m)                           \
        _Pragma("unroll") for (int kk = 0; kk < 2; ++kk) {                      \
            half8 h;                                                            \
            h[0] = (_Float16)ar[bi][m][kk][0].x; h[1] = (_Float16)ar[bi][m][kk][0].y; \
            h[2] = (_Float16)ar[bi][m][kk][0].z; h[3] = (_Float16)ar[bi][m][kk][0].w; \
            h[4] = (_Float16)ar[bi][m][kk][1].x; h[5] = (_Float16)ar[bi][m][kk][1].y; \
            h[6] = (_Float16)ar[bi][m][kk][1].z; h[7] = (_Float16)ar[bi][m][kk][1].w; \
            af[m][kk] = h;                                                      \
        }                                                                       \
    }
#define LOAD_B(kt)                                                              \
    {                                                                           \
        const half8* s_ = (const half8*)(pb + (kt) * 64);                       \
        _Pragma("unroll") for (int j = 0; j < 4; ++j) bst[j] = s_[j];           \
    }
#define WRITE_B(buf)                                                            \
    {                                                                           \
        _Pragma("unroll") for (int j = 0; j < 4; ++j)                           \
            *(half8*)(&sm.Bs[buf][bcol][bko + j * 8]) = bst[j];                 \
    }
#define MFMA_STEP(cur)                                                          \
    {                                                                           \
        _Pragma("unroll") for (int kk = 0; kk < 2; ++kk) {                      \
            half8 a0 = af[0][kk], a1 = af[1][kk];                               \
            _Pragma("unroll") for (int nn = 0; nn < 8; ++nn) {                  \
                half8 bb = *(const half8*)(&sm.Bs[cur][nn * 16 + (lane & 15)][kk * 32 + kbase]); \
                acc[0][nn] = __builtin_amdgcn_mfma_f32_16x16x32_f16(a0, bb, acc[0][nn], 0, 0, 0); \
                acc[1][nn] = __builtin_amdgcn_mfma_f32_16x16x32_f16(a1, bb, acc[1][nn], 0, 0, 0); \
            }                                                                   \
        }                                                                       \
    }
// lgkm-only barrier: LDS writes fenced; global loads stay in flight (no vmcnt drain)
#define LBAR()                                                                  \
    {                                                                           \
        asm volatile("s_waitcnt lgkmcnt(0)" ::: "memory");                      \
        __builtin_amdgcn_s_barrier();                                           \
    }

    // prologue: B(0), A(0), A(1) in flight; convert A(0); stage B(0)
    LOAD_B(0);
    LOAD_A(0, 0);
    LOAD_A(1, 1);
    CVT_A(0);            // waits A(0) (and B(0),A(0) drained: oldest-first)
    WRITE_B(0);
    LBAR();

#pragma unroll 1
    for (int kt = 0; kt < 14; ++kt) {
        const int cur = kt & 1;
        LOAD_B(kt + 1);                  // B(kt+1) -> bst
        LOAD_A(cur, kt + 2);             // A(kt+2) -> ar[cur] (A(kt) dead)
        MFMA_STEP(cur);                  // consume Bs[cur], af=A(kt)
        CVT_A(cur ^ 1);                  // af = A(kt+1); waits its loads only
        WRITE_B(cur ^ 1);                // stage B(kt+1); waits bst only
        LBAR();                          // A(kt+2) survives the barrier
    }
    // kt = 14
    LOAD_B(15);
    MFMA_STEP(0);
    CVT_A(1);                            // af = A(15)
    WRITE_B(1);
    LBAR();
    // kt = 15
    MFMA_STEP(1);

#undef LOAD_A
#undef CVT_A
#undef LOAD_B
#undef WRITE_B
#undef MFMA_STEP
#undef LBAR

    int colb = lane & 15, rgrp = (lane >> 4) * 4;
#pragma unroll
    for (int m = 0; m < 2; ++m) {
#pragma unroll
        for (int r = 0; r < 4; ++r) {
            int grow = brow0 + wid * 32 + m * 16 + rgrp + r;
            if (grow < M) {
                _Float16* hp = H + (size_t)grow * FEAT + colb;
#pragma unroll
                for (int nn = 0; nn < 8; ++nn) hp[nn * 16] = (_Float16)acc[m][nn][r];
            }
        }
    }
}

// agg1 + b1 + relu + @W2, Yd out. Wave per node; 4 gathers in flight per lane.
__global__ __launch_bounds__(256) void k_agg1(const _Float16* __restrict__ H,
                                              const int* __restrict__ csr,
                                              const int* __restrict__ cnt,
                                              const float* __restrict__ dinvarr,
                                              const float* __restrict__ b1,
                                              const float* __restrict__ W2,
                                              float* __restrict__ Y, int n) {
    int wid = threadIdx.x >> 6, lane = threadIdx.x & 63;
    int i = blockIdx.x * 4 + wid;
    if (i >= n) return;
    const int g = lane >> 4, u = lane & 15;
    int m = cnt[i];
    float di = dinvarr[i];

    int sl; float dl;
    if (lane < m) { sl = csr[(i << 6) + lane]; dl = dinvarr[sl]; }
    else          { sl = i;                    dl = (lane == m) ? di : 0.f; }
    int mm = (m < 63 ? m : 63) + 1;   // entries incl. self

    float ax[8];
#pragma unroll
    for (int j = 0; j < 8; ++j) ax[j] = 0.f;

    for (int e = 0; e < mm; e += 16) {
        int idx0 = e + g, idx1 = e + 4 + g, idx2 = e + 8 + g, idx3 = e + 12 + g;
        bool v0 = idx0 < mm, v1 = idx1 < mm, v2 = idx2 < mm, v3 = idx3 < mm;
        int c0i = v0 ? idx0 : 0, c1i = v1 ? idx1 : 0;
        int c2i = v2 ? idx2 : 0, c3i = v3 ? idx3 : 0;
        int s0 = __shfl(sl, c0i); float w0 = __shfl(dl, c0i);
        int s1 = __shfl(sl, c1i); float w1 = __shfl(dl, c1i);
        int s2 = __shfl(sl, c2i); float w2 = __shfl(dl, c2i);
        int s3 = __shfl(sl, c3i); float w3 = __shfl(dl, c3i);
        if (!v0) { s0 = i; w0 = 0.f; }
        if (!v1) { s1 = i; w1 = 0.f; }
        if (!v2) { s2 = i; w2 = 0.f; }
        if (!v3) { s3 = i; w3 = 0.f; }
        half8 h0 = *(const half8*)(H + ((size_t)s0 << 7) + u * 8);
        half8 h1 = *(const half8*)(H + ((size_t)s1 << 7) + u * 8);
        half8 h2 = *(const half8*)(H + ((size_t)s2 << 7) + u * 8);
        half8 h3 = *(const half8*)(H + ((size_t)s3 << 7) + u * 8);
#pragma unroll
        for (int j = 0; j < 8; ++j)
            ax[j] += w0 * (float)h0[j] + w1 * (float)h1[j]
                   + w2 * (float)h2[j] + w3 * (float)h3[j];
    }

#pragma unroll
    for (int j = 0; j < 8; ++j) {
        ax[j] += __shfl_xor(ax[j], 16);
        ax[j] += __shfl_xor(ax[j], 32);
    }

    int c0 = u * 8;
    float y0 = 0.f, y1 = 0.f, y2 = 0.f;
#pragma unroll
    for (int j = 0; j < 8; ++j) {
        float x = di * ax[j] + b1[c0 + j];
        x = x > 0.f ? x : 0.f;
        y0 += x * W2[(c0 + j) * 3 + 0];
        y1 += x * W2[(c0 + j) * 3 + 1];
        y2 += x * W2[(c0 + j) * 3 + 2];
    }
#pragma unroll
    for (int d = 1; d < 16; d <<= 1) {
        y0 += __shfl_xor(y0, d);
        y1 += __shfl_xor(y1, d);
        y2 += __shfl_xor(y2, d);
    }
    if (lane == 0) {
        float* yp = Y + (size_t)i * 4;
        yp[0] = di * y0; yp[1] = di * y1; yp[2] = di * y2;
    }
}

// agg2: out_i = dinv_i * (sum Yd_j + Yd_i) + b2 ; 4 loads in flight
__global__ void k_agg2(const float* __restrict__ Y, const int* __restrict__ csr,
                       const int* __restrict__ cnt, const float* __restrict__ dinvarr,
                       const float* __restrict__ b2, float* __restrict__ out, int n) {
    int i = blockIdx.x * 256 + threadIdx.x;
    if (i >= n) return;
    int m = cnt[i];
    float di = dinvarr[i];
    int base = i << 6;
    const float4* Y4 = (const float4*)Y;
    float4 self = Y4[i];
    float a0 = self.x, a1 = self.y, a2 = self.z;
    int e = 0;
    for (; e + 3 < m; e += 4) {
        int s0 = csr[base + e],     s1 = csr[base + e + 1];
        int s2 = csr[base + e + 2], s3 = csr[base + e + 3];
        float4 v0 = Y4[s0], v1 = Y4[s1], v2 = Y4[s2], v3 = Y4[s3];
        a0 += (v0.x + v1.x) + (v2.x + v3.x);
        a1 += (v0.y + v1.y) + (v2.y + v3.y);
        a2 += (v0.z + v1.z) + (v2.z + v3.z);
    }
    for (; e < m; ++e) {
        float4 v0 = Y4[csr[base + e]];
        a0 += v0.x; a1 += v0.y; a2 += v0.z;
    }
    out[(size_t)i * 3 + 0] = di * a0 + b2[0];
    out[(size_t)i * 3 + 1] = di * a1 + b2[1];
    out[(size_t)i * 3 + 2] = di * a2 + b2[2];
}

extern "C" void kernel_launch(void* const* d_in, const int* in_sizes, int n_in,
                              void* d_out, int out_size, void* d_ws, size_t ws_size,
                              hipStream_t stream) {
    const float* features = (const float*)d_in[0];
    const int* edges2 = (const int*)d_in[2];   // int64 in reference -> int32 on device
    const float* W1 = (const float*)d_in[5];
    const float* b1 = (const float*)d_in[6];
    const float* W2 = (const float*)d_in[7];
    const float* b2 = (const float*)d_in[8];
    float* out = (float*)d_out;

    const int N = N_NODES, E = N_EDGES;
    const int4* src4 = (const int4*)edges2;
    const int4* dst4 = (const int4*)(edges2 + E);
    int e4 = E / 4;

    char* p = (char*)d_ws;
    auto carve = [&](size_t bytes) { char* q = p; p += (bytes + 255) & ~(size_t)255; return q; };
    int* cnt       = (int*)carve(4 * (size_t)N);
    float* dinvarr = (float*)carve(4 * (size_t)N);
    int* cursorC   = (int*)carve(4 * NDIG);
    int* done      = (int*)carve(4);
    uint2* recs    = (uint2*)carve(8 * (size_t)NDIG * CAPC);
    int* csr       = (int*)carve(4 * (size_t)N * CAP);
    _Float16* W1t  = (_Float16*)carve(2 * (size_t)IN_CH * FEAT);
    _Float16* H    = (_Float16*)carve(2 * (size_t)N * FEAT);
    float* Y       = (float*)carve(16 * (size_t)N);

    k_prep<<<dim3(512), dim3(256), 0, stream>>>(W1, W1t, cursorC, done);
    k_build_gemm<<<dim3(NDIG + NTILES), dim3(256), 0, stream>>>(
        features, W1t, src4, dst4, cursorC, recs, csr, cnt, dinvarr, done, H, N, e4, 1);
    // attribution rider: identical GEMM-only relaunch (idempotent H rewrite).
    // dur_us delta vs next round (without this) == exact GEMM time.
    k_build_gemm<<<dim3(NDIG + NTILES), dim3(256), 0, stream>>>(
        features, W1t, src4, dst4, cursorC, recs, csr, cnt, dinvarr, done, H, N, e4, 0);
    k_agg1<<<dim3((N + 3) / 4), dim3(256), 0, stream>>>(H, csr, cnt, dinvarr, b1, W2, Y, N);
    k_agg2<<<dim3((N + 255) / 256), dim3(256), 0, stream>>>(Y, csr, cnt, dinvarr, b2, out, N);
}

// Round 14
// 252.609 us; speedup vs baseline: 3.0547x; 3.0547x over previous
//
#include <hip/hip_runtime.h>
#include <hip/hip_bf16.h>

typedef __attribute__((ext_vector_type(8))) _Float16 half8;
typedef __attribute__((ext_vector_type(4))) _Float16 half4;
typedef __attribute__((ext_vector_type(4))) float f32x4;

#define N_NODES 100000
#define N_EDGES 1600000
#define IN_CH 1024
#define FEAT 128
#define CAP 64
#define NDIG 196               // coarse digits: dst>>9
#define CAPC 10240             // coarse segment capacity
#define NTILES ((N_NODES + 127) / 128)   // 782

// Swizzled LDS byte offset: row stride 128 B (64 fp16), XOR bank swizzle.
// Uniform bank load for 8B/16B writes and b128 fragment reads (derived R14).
__device__ __forceinline__ int swz(int row, int colbyte) {
    return row * 128 + (colbyte ^ ((row & 7) << 4));
}

// W1t[col][k] = fp16 W1[k][col]; init coarse cursors + done flag
__global__ void k_prep(const float* __restrict__ W1, _Float16* __restrict__ W1t,
                       int* __restrict__ cursorC, int* __restrict__ done) {
    int idx = blockIdx.x * 256 + threadIdx.x;
    if (idx < IN_CH * FEAT) {
        int col = idx & (FEAT - 1), k = idx >> 7;
        W1t[(size_t)col * IN_CH + k] = (_Float16)W1[idx];
    }
    if (idx < NDIG) cursorC[idx] = idx * CAPC;
    if (idx == 0) *done = 0;
}

// Role-split kernel:
//  blocks [0,NDIG):        bin -> resident spin -> exact CSR (+cnt +dinvarr)  (~7us)
//  blocks [NDIG,+NTILES):  H = A @ W1, fp16 MFMA. A staged COALESCED (256B row
//                          segments) into XOR-swizzled LDS; B same. dbuf, 1 barrier.
__global__ __launch_bounds__(256, 2) void k_build_gemm(
    const float* __restrict__ A, const _Float16* __restrict__ Bt,
    const int4* __restrict__ src4, const int4* __restrict__ dst4,
    int* __restrict__ cursorC, uint2* __restrict__ recs,
    int* __restrict__ csr, int* __restrict__ cnt, float* __restrict__ dinvarr,
    int* __restrict__ done, _Float16* __restrict__ H, int M, int e4)
{
    __shared__ union {
        struct { _Float16 As[2][128 * 64]; _Float16 Bsw[2][128 * 64]; } g;  // 64 KB
        struct { int hist[NDIG], segoff[NDIG], lcur[NDIG]; } bin;
        int cl[512];
    } sm;
    const int t = threadIdx.x;

    if (blockIdx.x < NDIG) {
        // ================= bin phase =================
        const int b = blockIdx.x;
        if (t < NDIG) sm.bin.hist[t] = 0;
        __syncthreads();
        const int base4 = b * 2048;
        int4 sv[8], dv[8];
#pragma unroll
        for (int j = 0; j < 8; ++j) {
            int idx = base4 + j * 256 + t;
            if (idx < e4) { sv[j] = src4[idx]; dv[j] = dst4[idx]; }
            else { sv[j] = (int4){-1,-1,-1,-1}; dv[j] = (int4){-1,-1,-1,-1}; }
        }
#pragma unroll
        for (int j = 0; j < 8; ++j) {
            int dd[4] = {dv[j].x, dv[j].y, dv[j].z, dv[j].w};
            int ss[4] = {sv[j].x, sv[j].y, sv[j].z, sv[j].w};
#pragma unroll
            for (int c = 0; c < 4; ++c)
                if ((unsigned)dd[c] < N_NODES && (unsigned)ss[c] < N_NODES)
                    atomicAdd(&sm.bin.hist[dd[c] >> 9], 1);
        }
        __syncthreads();
        if (t < NDIG) {
            sm.bin.segoff[t] = atomicAdd(&cursorC[t], sm.bin.hist[t]);
            sm.bin.lcur[t] = 0;
        }
        __syncthreads();
#pragma unroll
        for (int j = 0; j < 8; ++j) {
            int dd[4] = {dv[j].x, dv[j].y, dv[j].z, dv[j].w};
            int ss[4] = {sv[j].x, sv[j].y, sv[j].z, sv[j].w};
#pragma unroll
            for (int c = 0; c < 4; ++c) {
                if ((unsigned)dd[c] < N_NODES && (unsigned)ss[c] < N_NODES) {
                    int dg = dd[c] >> 9;
                    int r = atomicAdd(&sm.bin.lcur[dg], 1);
                    int pos = sm.bin.segoff[dg] + r;
                    if (pos < (dg + 1) * CAPC)
                        recs[pos] = (uint2){(unsigned)ss[c], (unsigned)dd[c]};
                }
            }
        }
        __syncthreads();
        if (t == 0) {   // resident spin-barrier over the 196 bin blocks
            __threadfence();
            __hip_atomic_fetch_add(done, 1, __ATOMIC_RELEASE, __HIP_MEMORY_SCOPE_AGENT);
            while (__hip_atomic_load(done, __ATOMIC_ACQUIRE, __HIP_MEMORY_SCOPE_AGENT) < NDIG)
                __builtin_amdgcn_s_sleep(8);
        }
        __syncthreads();
        // ================= csr phase =================
        const int d = blockIdx.x;
        for (int j = t; j < 512; j += 256) sm.cl[j] = 0;
        __syncthreads();
        const int base = d * CAPC;
        int n = cursorC[d] - base;
        if (n > CAPC) n = CAPC;
        for (int k = t; k < n; k += 256) {
            uint2 r = recs[base + k];
            int local = (int)r.y & 511;
            int slot = atomicAdd(&sm.cl[local], 1);
            if (slot < CAP) csr[((int)r.y << 6) + slot] = (int)r.x;
        }
        __syncthreads();
        const int node0 = d << 9;
        for (int j = t; j < 512; j += 256) {
            int node = node0 + j;
            if (node < N_NODES) {
                int c = sm.cl[j] < CAP ? sm.cl[j] : CAP;
                cnt[node] = c;
                dinvarr[node] = rsqrtf((float)(c + 1));
            }
        }
        return;
    }

    // ================= GEMM role =================
    const int wid = t >> 6, lane = t & 63;
    const int brow0 = (blockIdx.x - NDIG) * 128;

    f32x4 acc[2][8];
#pragma unroll
    for (int m = 0; m < 2; ++m)
#pragma unroll
        for (int nn = 0; nn < 8; ++nn) acc[m][nn] = (f32x4){0.f, 0.f, 0.f, 0.f};

    // A staging: instr i, thread t -> row brow0+i*16+(t>>4), cols (t&15)*4..+4 (f32).
    // 16 consecutive lanes read one CONTIGUOUS 256B row segment.
    const int sarow = t >> 4;            // 0..15
    const int sacolB = (t & 15) * 8;     // byte col (fp16) for LDS write
    const float* paBase[8];
#pragma unroll
    for (int i = 0; i < 8; ++i) {
        int grow = brow0 + i * 16 + sarow;
        if (grow >= M) grow = M - 1;
        paBase[i] = A + (size_t)grow * IN_CH + (t & 15) * 4;
    }
    // B staging: thread t covers row (t>>1), byte half (t&1)*64..+64
    const int bcol = t >> 1;
    const int bhalf = (t & 1) * 64;      // byte offset within 128B row
    const _Float16* pb = Bt + (size_t)bcol * IN_CH + (t & 1) * 32;

    float4 areg[8];
    half8 bst[4];

#define LOAD_AB(kt)                                                             \
    {                                                                           \
        _Pragma("unroll") for (int i = 0; i < 8; ++i)                           \
            areg[i] = *(const float4*)(paBase[i] + (kt) * 64);                  \
        const half8* s_ = (const half8*)(pb + (kt) * 64);                       \
        _Pragma("unroll") for (int j = 0; j < 4; ++j) bst[j] = s_[j];           \
    }
#define CVT_WRITE(buf)                                                          \
    {                                                                           \
        _Pragma("unroll") for (int i = 0; i < 8; ++i) {                         \
            half4 h;                                                            \
            h[0] = (_Float16)areg[i].x; h[1] = (_Float16)areg[i].y;             \
            h[2] = (_Float16)areg[i].z; h[3] = (_Float16)areg[i].w;             \
            *(half4*)((char*)sm.g.As[buf] + swz(i * 16 + sarow, sacolB)) = h;   \
        }                                                                       \
        _Pragma("unroll") for (int j = 0; j < 4; ++j)                           \
            *(half8*)((char*)sm.g.Bsw[buf] + swz(bcol, bhalf + j * 16)) = bst[j]; \
    }
#define MFMA_STEP(cur)                                                          \
    {                                                                           \
        _Pragma("unroll") for (int kk = 0; kk < 2; ++kk) {                      \
            const int cb = kk * 64 + (lane >> 4) * 16;                          \
            half8 a0 = *(const half8*)((char*)sm.g.As[cur] + swz(wid * 32 + (lane & 15), cb)); \
            half8 a1 = *(const half8*)((char*)sm.g.As[cur] + swz(wid * 32 + 16 + (lane & 15), cb)); \
            _Pragma("unroll") for (int nn = 0; nn < 8; ++nn) {                  \
                half8 bb = *(const half8*)((char*)sm.g.Bsw[cur] + swz(nn * 16 + (lane & 15), cb)); \
                acc[0][nn] = __builtin_amdgcn_mfma_f32_16x16x32_f16(a0, bb, acc[0][nn], 0, 0, 0); \
                acc[1][nn] = __builtin_amdgcn_mfma_f32_16x16x32_f16(a1, bb, acc[1][nn], 0, 0, 0); \
            }                                                                   \
        }                                                                       \
    }

    LOAD_AB(0);
    CVT_WRITE(0);
    __syncthreads();

#pragma unroll 1
    for (int kt = 0; kt < 16; ++kt) {
        const int cur = kt & 1;
        if (kt + 1 < 16) LOAD_AB(kt + 1);     // next-tile loads in flight over MFMA
        MFMA_STEP(cur);
        if (kt + 1 < 16) {
            CVT_WRITE(cur ^ 1);
            __syncthreads();
        }
    }
#undef LOAD_AB
#undef CVT_WRITE
#undef MFMA_STEP

    int colb = lane & 15, rgrp = (lane >> 4) * 4;
#pragma unroll
    for (int m = 0; m < 2; ++m) {
#pragma unroll
        for (int r = 0; r < 4; ++r) {
            int grow = brow0 + wid * 32 + m * 16 + rgrp + r;
            if (grow < M) {
                _Float16* hp = H + (size_t)grow * FEAT + colb;
#pragma unroll
                for (int nn = 0; nn < 8; ++nn) hp[nn * 16] = (_Float16)acc[m][nn][r];
            }
        }
    }
}

// agg1 + b1 + relu + @W2, Yd out. Wave per node; 4 gathers in flight per lane.
__global__ __launch_bounds__(256) void k_agg1(const _Float16* __restrict__ H,
                                              const int* __restrict__ csr,
                                              const int* __restrict__ cnt,
                                              const float* __restrict__ dinvarr,
                                              const float* __restrict__ b1,
                                              const float* __restrict__ W2,
                                              float* __restrict__ Y, int n) {
    int wid = threadIdx.x >> 6, lane = threadIdx.x & 63;
    int i = blockIdx.x * 4 + wid;
    if (i >= n) return;
    const int g = lane >> 4, u = lane & 15;
    int m = cnt[i];
    float di = dinvarr[i];

    int sl; float dl;
    if (lane < m) { sl = csr[(i << 6) + lane]; dl = dinvarr[sl]; }
    else          { sl = i;                    dl = (lane == m) ? di : 0.f; }
    int mm = (m < 63 ? m : 63) + 1;   // entries incl. self

    float ax[8];
#pragma unroll
    for (int j = 0; j < 8; ++j) ax[j] = 0.f;

    for (int e = 0; e < mm; e += 16) {
        int idx0 = e + g, idx1 = e + 4 + g, idx2 = e + 8 + g, idx3 = e + 12 + g;
        bool v0 = idx0 < mm, v1 = idx1 < mm, v2 = idx2 < mm, v3 = idx3 < mm;
        int c0i = v0 ? idx0 : 0, c1i = v1 ? idx1 : 0;
        int c2i = v2 ? idx2 : 0, c3i = v3 ? idx3 : 0;
        int s0 = __shfl(sl, c0i); float w0 = __shfl(dl, c0i);
        int s1 = __shfl(sl, c1i); float w1 = __shfl(dl, c1i);
        int s2 = __shfl(sl, c2i); float w2 = __shfl(dl, c2i);
        int s3 = __shfl(sl, c3i); float w3 = __shfl(dl, c3i);
        if (!v0) { s0 = i; w0 = 0.f; }
        if (!v1) { s1 = i; w1 = 0.f; }
        if (!v2) { s2 = i; w2 = 0.f; }
        if (!v3) { s3 = i; w3 = 0.f; }
        half8 h0 = *(const half8*)(H + ((size_t)s0 << 7) + u * 8);
        half8 h1 = *(const half8*)(H + ((size_t)s1 << 7) + u * 8);
        half8 h2 = *(const half8*)(H + ((size_t)s2 << 7) + u * 8);
        half8 h3 = *(const half8*)(H + ((size_t)s3 << 7) + u * 8);
#pragma unroll
        for (int j = 0; j < 8; ++j)
            ax[j] += w0 * (float)h0[j] + w1 * (float)h1[j]
                   + w2 * (float)h2[j] + w3 * (float)h3[j];
    }

#pragma unroll
    for (int j = 0; j < 8; ++j) {
        ax[j] += __shfl_xor(ax[j], 16);
        ax[j] += __shfl_xor(ax[j], 32);
    }

    int c0 = u * 8;
    float y0 = 0.f, y1 = 0.f, y2 = 0.f;
#pragma unroll
    for (int j = 0; j < 8; ++j) {
        float x = di * ax[j] + b1[c0 + j];
        x = x > 0.f ? x : 0.f;
        y0 += x * W2[(c0 + j) * 3 + 0];
        y1 += x * W2[(c0 + j) * 3 + 1];
        y2 += x * W2[(c0 + j) * 3 + 2];
    }
#pragma unroll
    for (int d = 1; d < 16; d <<= 1) {
        y0 += __shfl_xor(y0, d);
        y1 += __shfl_xor(y1, d);
        y2 += __shfl_xor(y2, d);
    }
    if (lane == 0) {
        float* yp = Y + (size_t)i * 4;
        yp[0] = di * y0; yp[1] = di * y1; yp[2] = di * y2;
    }
}

// agg2: out_i = dinv_i * (sum Yd_j + Yd_i) + b2 ; 4 loads in flight
__global__ void k_agg2(const float* __restrict__ Y, const int* __restrict__ csr,
                       const int* __restrict__ cnt, const float* __restrict__ dinvarr,
                       const float* __restrict__ b2, float* __restrict__ out, int n) {
    int i = blockIdx.x * 256 + threadIdx.x;
    if (i >= n) return;
    int m = cnt[i];
    float di = dinvarr[i];
    int base = i << 6;
    const float4* Y4 = (const float4*)Y;
    float4 self = Y4[i];
    float a0 = self.x, a1 = self.y, a2 = self.z;
    int e = 0;
    for (; e + 3 < m; e += 4) {
        int s0 = csr[base + e],     s1 = csr[base + e + 1];
        int s2 = csr[base + e + 2], s3 = csr[base + e + 3];
        float4 v0 = Y4[s0], v1 = Y4[s1], v2 = Y4[s2], v3 = Y4[s3];
        a0 += (v0.x + v1.x) + (v2.x + v3.x);
        a1 += (v0.y + v1.y) + (v2.y + v3.y);
        a2 += (v0.z + v1.z) + (v2.z + v3.z);
    }
    for (; e < m; ++e) {
        float4 v0 = Y4[csr[base + e]];
        a0 += v0.x; a1 += v0.y; a2 += v0.z;
    }
    out[(size_t)i * 3 + 0] = di * a0 + b2[0];
    out[(size_t)i * 3 + 1] = di * a1 + b2[1];
    out[(size_t)i * 3 + 2] = di * a2 + b2[2];
}

extern "C" void kernel_launch(void* const* d_in, const int* in_sizes, int n_in,
                              void* d_out, int out_size, void* d_ws, size_t ws_size,
                              hipStream_t stream) {
    const float* features = (const float*)d_in[0];
    const int* edges2 = (const int*)d_in[2];   // int64 in reference -> int32 on device
    const float* W1 = (const float*)d_in[5];
    const float* b1 = (const float*)d_in[6];
    const float* W2 = (const float*)d_in[7];
    const float* b2 = (const float*)d_in[8];
    float* out = (float*)d_out;

    const int N = N_NODES, E = N_EDGES;
    const int4* src4 = (const int4*)edges2;
    const int4* dst4 = (const int4*)(edges2 + E);
    int e4 = E / 4;

    char* p = (char*)d_ws;
    auto carve = [&](size_t bytes) { char* q = p; p += (bytes + 255) & ~(size_t)255; return q; };
    int* cnt       = (int*)carve(4 * (size_t)N);
    float* dinvarr = (float*)carve(4 * (size_t)N);
    int* cursorC   = (int*)carve(4 * NDIG);
    int* done      = (int*)carve(4);
    uint2* recs    = (uint2*)carve(8 * (size_t)NDIG * CAPC);
    int* csr       = (int*)carve(4 * (size_t)N * CAP);
    _Float16* W1t  = (_Float16*)carve(2 * (size_t)IN_CH * FEAT);
    _Float16* H    = (_Float16*)carve(2 * (size_t)N * FEAT);
    float* Y       = (float*)carve(16 * (size_t)N);

    k_prep<<<dim3(512), dim3(256), 0, stream>>>(W1, W1t, cursorC, done);
    k_build_gemm<<<dim3(NDIG + NTILES), dim3(256), 0, stream>>>(
        features, W1t, src4, dst4, cursorC, recs, csr, cnt, dinvarr, done, H, N, e4);
    k_agg1<<<dim3((N + 3) / 4), dim3(256), 0, stream>>>(H, csr, cnt, dinvarr, b1, W2, Y, N);
    k_agg2<<<dim3((N + 255) / 256), dim3(256), 0, stream>>>(Y, csr, cnt, dinvarr, b2, out, N);
}